// Round 3
// baseline (671.289 us; speedup 1.0000x reference)
//
#include <hip/hip_runtime.h>
#include <hip/hip_bf16.h>
#include <math.h>

#define N_ATOMS 5000
#define N_EDGES 100000
#define F 128
#define B 20
#define NL 3
#define CAP 96

constexpr float CUTOFF = 5.0f;
constexpr float PI_F = 3.14159265358979323846f;

__device__ __forceinline__ float silu_f(float x) { return x / (1.0f + __expf(-x)); }

// ---------------------------------------------------------------- init: s = emb[Z]
__global__ void init_kernel(const int* __restrict__ Z, const float* __restrict__ emb,
                            float* __restrict__ s) {
    int atom = blockIdx.x;
    int t = threadIdx.x;
    s[atom * F + t] = emb[Z[atom] * F + t];
}

// ---------------------------------------------------------------- bucket edges by dst
__global__ void fill_buckets(const int* __restrict__ eidx, int* __restrict__ count,
                             int* __restrict__ bucket) {
    int e = blockIdx.x * 256 + threadIdx.x;
    if (e >= N_EDGES) return;
    int dst = eidx[2 * e];
    int pos = atomicAdd(&count[dst], 1);
    if (pos < CAP) bucket[dst * CAP + pos] = e;
}

// ---------------------------------------------------------------- phi = silu(s@W1+b1)@W2+b2
// 256 threads, 16 atoms/block; t = feature, h = atom-half (8 atoms each)
__global__ __launch_bounds__(256) void phi_kernel(
    const float* __restrict__ s, const float* __restrict__ w1, const float* __restrict__ b1,
    const float* __restrict__ w2, const float* __restrict__ b2, float* __restrict__ phi) {
    const int TA = 16;
    __shared__ __align__(16) float sh_s[F][20];
    __shared__ __align__(16) float sh_h[F][20];
    int a0 = blockIdx.x * TA;
    int t = threadIdx.x & 127;
    int h = threadIdx.x >> 7;   // 0..1
#pragma unroll
    for (int a = 0; a < 8; ++a) {
        int atom = a0 + h * 8 + a;
        sh_s[t][h * 8 + a] = (atom < N_ATOMS) ? s[atom * F + t] : 0.0f;
    }
    __syncthreads();
    float acc[8];
    float bb = b1[t];
#pragma unroll
    for (int a = 0; a < 8; ++a) acc[a] = bb;
#pragma unroll 16
    for (int k = 0; k < F; ++k) {
        float w = w1[k * F + t];
        const float* rp = &sh_s[k][h * 8];
        float4 q0 = *(const float4*)rp, q1 = *(const float4*)(rp + 4);
        float sv[8] = {q0.x, q0.y, q0.z, q0.w, q1.x, q1.y, q1.z, q1.w};
#pragma unroll
        for (int a = 0; a < 8; ++a) acc[a] += sv[a] * w;
    }
#pragma unroll
    for (int a = 0; a < 8; ++a) sh_h[t][h * 8 + a] = silu_f(acc[a]);
    __syncthreads();
    float A0[8], A1[8], A2[8];
    float c0 = b2[t], c1 = b2[F + t], c2 = b2[2 * F + t];
#pragma unroll
    for (int a = 0; a < 8; ++a) { A0[a] = c0; A1[a] = c1; A2[a] = c2; }
#pragma unroll 8
    for (int k = 0; k < F; ++k) {
        const float* wr = w2 + k * 3 * F;
        float w0 = wr[t], w1v = wr[F + t], w2v = wr[2 * F + t];
        const float* rp = &sh_h[k][h * 8];
        float4 q0 = *(const float4*)rp, q1 = *(const float4*)(rp + 4);
        float hv[8] = {q0.x, q0.y, q0.z, q0.w, q1.x, q1.y, q1.z, q1.w};
#pragma unroll
        for (int a = 0; a < 8; ++a) {
            A0[a] += hv[a] * w0; A1[a] += hv[a] * w1v; A2[a] += hv[a] * w2v;
        }
    }
#pragma unroll
    for (int a = 0; a < 8; ++a) {
        int atom = a0 + h * 8 + a;
        if (atom < N_ATOMS) {
            float* po = phi + atom * 3 * F;
            po[t] = A0[a]; po[F + t] = A1[a]; po[2 * F + t] = A2[a];
        }
    }
}

// ---------------------------------------------------------------- per-dst edge aggregation
// software-pipelined gathers: double-buffered groups of 4 edges
__global__ __launch_bounds__(128) void edge_agg_kernel(
    const int* __restrict__ count, const int* __restrict__ bucket,
    const int* __restrict__ eidx, const float* __restrict__ ediff,
    const float* __restrict__ edist,
    const float* __restrict__ fw, const float* __restrict__ fb,
    const float* __restrict__ phi, const float* __restrict__ v,
    float* __restrict__ ds, float* __restrict__ dv) {
    int a = blockIdx.x;
    int t = threadIdx.x;

    float rfw0[B], rfw1[B], rfw2[B];
#pragma unroll
    for (int b = 0; b < B; ++b) {
        const float* row = fw + b * 3 * F;
        rfw0[b] = row[t]; rfw1[b] = row[F + t]; rfw2[b] = row[2 * F + t];
    }
    float fb0 = fb[t], fb1 = fb[F + t], fb2 = fb[2 * F + t];

    int n = count[a]; if (n > CAP) n = CAP;
    float accS = 0.f, accV0 = 0.f, accV1 = 0.f, accV2 = 0.f;

    __shared__ __align__(16) float sh_rbf[32][B];
    __shared__ float sh_env[32];
    __shared__ float sh_unit[32][3];
    __shared__ int sh_src[32];
    const int* bptr = bucket + a * CAP;

    for (int base = 0; base < n; base += 32) {
        int cnt = min(32, n - base);
        __syncthreads();
        if (t < cnt) {
            int e = bptr[base + t];
            sh_src[t] = eidx[2 * e + 1];
            float d = edist[e];
            float fc = 0.5f * (cosf(PI_F * d / CUTOFF) + 1.0f);
            sh_env[t] = (d < CUTOFF) ? fc : 0.0f;
            float inv = 1.0f / d;
            sh_unit[t][0] = ediff[3 * e + 0] * inv;
            sh_unit[t][1] = ediff[3 * e + 1] * inv;
            sh_unit[t][2] = ediff[3 * e + 2] * inv;
        }
        for (int task = t; task < cnt * B; task += 128) {
            int i = task / B, b = task - i * B;
            int e = bptr[base + i];
            float d = edist[e];
            sh_rbf[i][b] = sinf(d * (float)(b + 1) * (PI_F / CUTOFF)) / d;
        }
        __syncthreads();

        float PA[4][3], VA[4][3], PB[4][3], VB[4][3];
        int ngrp = (cnt + 3) >> 2;

        auto load_grp = [&](int gbase, float P[4][3], float V4[4][3]) {
#pragma unroll
            for (int j = 0; j < 4; ++j) {
                int i = gbase + j;
                int ii = (i < cnt) ? i : (cnt - 1);
                int src = sh_src[ii];
                const float* ps = phi + src * 3 * F;
                const float* vs = v + src * 3 * F;
                P[j][0] = ps[t]; P[j][1] = ps[F + t]; P[j][2] = ps[2 * F + t];
                V4[j][0] = vs[t]; V4[j][1] = vs[F + t]; V4[j][2] = vs[2 * F + t];
            }
        };
        auto comp_grp = [&](int gbase, float P[4][3], float V4[4][3]) {
#pragma unroll
            for (int j = 0; j < 4; ++j) {
                int i = gbase + j;
                if (i < cnt) {
                    float f0 = fb0, f1 = fb1, f2 = fb2;
#pragma unroll
                    for (int b = 0; b < B; ++b) {
                        float r = sh_rbf[i][b];
                        f0 += r * rfw0[b]; f1 += r * rfw1[b]; f2 += r * rfw2[b];
                    }
                    float env = sh_env[i];
                    f0 *= env; f1 *= env; f2 *= env;
                    accS += f2 * P[j][2];
                    float gsv = f0 * P[j][0], gev = f1 * P[j][1];
                    accV0 += V4[j][0] * gsv + gev * sh_unit[i][0];
                    accV1 += V4[j][1] * gsv + gev * sh_unit[i][1];
                    accV2 += V4[j][2] * gsv + gev * sh_unit[i][2];
                }
            }
        };

        load_grp(0, PA, VA);
        for (int g = 0; g < ngrp; g += 2) {
            if (g + 1 < ngrp) load_grp((g + 1) * 4, PB, VB);
            comp_grp(g * 4, PA, VA);
            if (g + 1 < ngrp) {
                if (g + 2 < ngrp) load_grp((g + 2) * 4, PA, VA);
                comp_grp((g + 1) * 4, PB, VB);
            }
        }
    }
    ds[a * F + t] = accS;
    float* dvd = dv + a * 3 * F;
    dvd[t] = accV0; dvd[F + t] = accV1; dvd[2 * F + t] = accV2;
}

// ---------------------------------------------------------------- per-atom update
// 256 threads, 8 atoms/block; t = feature, h = atom-half (4 atoms each)
__global__ __launch_bounds__(256) void update_kernel(
    float* __restrict__ s, float* __restrict__ v,
    const float* __restrict__ ds, const float* __restrict__ dv,
    const float* __restrict__ U, const float* __restrict__ V,
    const float* __restrict__ w1, const float* __restrict__ b1,
    const float* __restrict__ w2, const float* __restrict__ b2) {
    const int TA = 8;
    __shared__ __align__(16) float sh_s[F][12];
    __shared__ __align__(16) float sh_vn[F][12];
    __shared__ __align__(16) float sh_h[F][12];
    __shared__ __align__(16) float sh_v[3][F][12];
    int a0 = blockIdx.x * TA;
    int t = threadIdx.x & 127;
    int h = threadIdx.x >> 7;   // 0..1
    float sn[4];
#pragma unroll
    for (int a = 0; a < 4; ++a) {
        int atom = a0 + h * 4 + a;
        sn[a] = s[atom * F + t] + ds[atom * F + t];
        sh_s[t][h * 4 + a] = sn[a];
#pragma unroll
        for (int d = 0; d < 3; ++d)
            sh_v[d][t][h * 4 + a] = v[atom * 3 * F + d * F + t] + dv[atom * 3 * F + d * F + t];
    }
    __syncthreads();
    float uv[3][4], vv[3][4];
#pragma unroll
    for (int d = 0; d < 3; ++d)
#pragma unroll
        for (int a = 0; a < 4; ++a) { uv[d][a] = 0.f; vv[d][a] = 0.f; }
#pragma unroll 8
    for (int k = 0; k < F; ++k) {
        float uu = U[k * F + t], wv = V[k * F + t];
#pragma unroll
        for (int d = 0; d < 3; ++d) {
            float4 q = *(const float4*)&sh_v[d][k][h * 4];
            float xv[4] = {q.x, q.y, q.z, q.w};
#pragma unroll
            for (int a = 0; a < 4; ++a) { uv[d][a] += xv[a] * uu; vv[d][a] += xv[a] * wv; }
        }
    }
#pragma unroll
    for (int a = 0; a < 4; ++a)
        sh_vn[t][h * 4 + a] = sqrtf(vv[0][a] * vv[0][a] + vv[1][a] * vv[1][a] + vv[2][a] * vv[2][a]);
    __syncthreads();
    float hh[4];
    float bb = b1[t];
#pragma unroll
    for (int a = 0; a < 4; ++a) hh[a] = bb;
#pragma unroll 8
    for (int k = 0; k < F; ++k) {
        float wa = w1[k * F + t], wb = w1[(F + k) * F + t];
        float4 qs = *(const float4*)&sh_s[k][h * 4];
        float4 qn = *(const float4*)&sh_vn[k][h * 4];
        hh[0] += qs.x * wa + qn.x * wb;
        hh[1] += qs.y * wa + qn.y * wb;
        hh[2] += qs.z * wa + qn.z * wb;
        hh[3] += qs.w * wa + qn.w * wb;
    }
#pragma unroll
    for (int a = 0; a < 4; ++a) sh_h[t][h * 4 + a] = silu_f(hh[a]);
    __syncthreads();
    float A0[4], A1[4], A2[4];
    float c0 = b2[t], c1 = b2[F + t], c2 = b2[2 * F + t];
#pragma unroll
    for (int a = 0; a < 4; ++a) { A0[a] = c0; A1[a] = c1; A2[a] = c2; }
#pragma unroll 8
    for (int k = 0; k < F; ++k) {
        const float* wr = w2 + k * 3 * F;
        float w0 = wr[t], w1v = wr[F + t], w2v = wr[2 * F + t];
        float4 q = *(const float4*)&sh_h[k][h * 4];
        float hv[4] = {q.x, q.y, q.z, q.w};
#pragma unroll
        for (int a = 0; a < 4; ++a) {
            A0[a] += hv[a] * w0; A1[a] += hv[a] * w1v; A2[a] += hv[a] * w2v;
        }
    }
#pragma unroll
    for (int a = 0; a < 4; ++a) {
        int atom = a0 + h * 4 + a;
        float dot = uv[0][a] * vv[0][a] + uv[1][a] * vv[1][a] + uv[2][a] * vv[2][a];
#pragma unroll
        for (int d = 0; d < 3; ++d)
            v[atom * 3 * F + d * F + t] = sh_v[d][t][h * 4 + a] + A0[a] * uv[d][a];
        s[atom * F + t] = sn[a] + A1[a] * dot + A2[a];
    }
}

// ---------------------------------------------------------------- readout, 16 atoms/block, 64 threads
__global__ __launch_bounds__(64) void readout_kernel(
    const float* __restrict__ s, const float* __restrict__ w1, const float* __restrict__ b1,
    const float* __restrict__ w2, const float* __restrict__ b2, float* __restrict__ out) {
    const int TA = 16;
    __shared__ __align__(16) float sh_s[F][20];
    int a0 = blockIdx.x * TA;
    int t = threadIdx.x;  // 0..63
#pragma unroll
    for (int a = 0; a < TA; ++a) {
        int atom = a0 + a;
        sh_s[t][a]      = (atom < N_ATOMS) ? s[atom * F + t] : 0.0f;
        sh_s[t + 64][a] = (atom < N_ATOMS) ? s[atom * F + 64 + t] : 0.0f;
    }
    __syncthreads();
    float acc[TA];
    float bb = b1[t];
#pragma unroll
    for (int a = 0; a < TA; ++a) acc[a] = bb;
#pragma unroll 8
    for (int k = 0; k < F; ++k) {
        float w = w1[k * 64 + t];
        const float* rp = &sh_s[k][0];
        float4 q0 = *(const float4*)(rp), q1 = *(const float4*)(rp + 4);
        float4 q2 = *(const float4*)(rp + 8), q3 = *(const float4*)(rp + 12);
        float sv[TA] = {q0.x, q0.y, q0.z, q0.w, q1.x, q1.y, q1.z, q1.w,
                        q2.x, q2.y, q2.z, q2.w, q3.x, q3.y, q3.z, q3.w};
#pragma unroll
        for (int a = 0; a < TA; ++a) acc[a] += sv[a] * w;
    }
    float w2t = w2[t];
    float p[TA];
#pragma unroll
    for (int a = 0; a < TA; ++a) p[a] = silu_f(acc[a]) * w2t;
#pragma unroll
    for (int a = 0; a < TA; ++a)
#pragma unroll
        for (int off = 32; off > 0; off >>= 1) p[a] += __shfl_down(p[a], off, 64);
    if (t == 0) {
        float bias = b2[0];
#pragma unroll
        for (int a = 0; a < TA; ++a) {
            int atom = a0 + a;
            if (atom < N_ATOMS) out[atom] = p[a] + bias;
        }
    }
}

extern "C" void kernel_launch(void* const* d_in, const int* in_sizes, int n_in,
                              void* d_out, int out_size, void* d_ws, size_t ws_size,
                              hipStream_t stream) {
    const int*   Z      = (const int*)d_in[0];
    const int*   eidx   = (const int*)d_in[1];
    const float* ediff  = (const float*)d_in[2];
    const float* edist  = (const float*)d_in[3];
    const float* emb    = (const float*)d_in[4];
    const float* msg_w1 = (const float*)d_in[5];
    const float* msg_b1 = (const float*)d_in[6];
    const float* msg_w2 = (const float*)d_in[7];
    const float* msg_b2 = (const float*)d_in[8];
    const float* filt_w = (const float*)d_in[9];
    const float* filt_b = (const float*)d_in[10];
    const float* upd_U  = (const float*)d_in[11];
    const float* upd_V  = (const float*)d_in[12];
    const float* upd_w1 = (const float*)d_in[13];
    const float* upd_b1 = (const float*)d_in[14];
    const float* upd_w2 = (const float*)d_in[15];
    const float* upd_b2 = (const float*)d_in[16];
    const float* ro_w1  = (const float*)d_in[17];
    const float* ro_b1  = (const float*)d_in[18];
    const float* ro_w2  = (const float*)d_in[19];
    const float* ro_b2  = (const float*)d_in[20];
    float* out = (float*)d_out;

    float* ws  = (float*)d_ws;
    float* s    = ws;                     // N*F
    float* v    = s + N_ATOMS * F;        // N*3F
    float* phi  = v + N_ATOMS * 3 * F;    // N*3F
    float* ds   = phi + N_ATOMS * 3 * F;  // N*F
    float* dv   = ds + N_ATOMS * F;       // N*3F
    int* count  = (int*)(dv + N_ATOMS * 3 * F);  // N
    int* bucket = count + N_ATOMS;               // N*CAP

    init_kernel<<<N_ATOMS, F, 0, stream>>>(Z, emb, s);
    hipMemsetAsync(v, 0, (size_t)N_ATOMS * 3 * F * sizeof(float), stream);
    hipMemsetAsync(count, 0, (size_t)N_ATOMS * sizeof(int), stream);
    fill_buckets<<<(N_EDGES + 255) / 256, 256, 0, stream>>>(eidx, count, bucket);

    for (int l = 0; l < NL; ++l) {
        phi_kernel<<<(N_ATOMS + 15) / 16, 256, 0, stream>>>(
            s, msg_w1 + l * F * F, msg_b1 + l * F,
            msg_w2 + l * F * 3 * F, msg_b2 + l * 3 * F, phi);
        edge_agg_kernel<<<N_ATOMS, 128, 0, stream>>>(
            count, bucket, eidx, ediff, edist,
            filt_w + l * B * 3 * F, filt_b + l * 3 * F, phi, v, ds, dv);
        update_kernel<<<N_ATOMS / 8, 256, 0, stream>>>(
            s, v, ds, dv, upd_U + l * F * F, upd_V + l * F * F,
            upd_w1 + l * 2 * F * F, upd_b1 + l * F,
            upd_w2 + l * F * 3 * F, upd_b2 + l * 3 * F);
    }
    readout_kernel<<<(N_ATOMS + 15) / 16, 64, 0, stream>>>(s, ro_w1, ro_b1, ro_w2, ro_b2, out);
}

// Round 4
// 609.993 us; speedup vs baseline: 1.1005x; 1.1005x over previous
//
#include <hip/hip_runtime.h>
#include <hip/hip_bf16.h>
#include <math.h>

#define N_ATOMS 5000
#define N_EDGES 100000
#define F 128
#define B 20
#define NL 3
#define CAP 96

constexpr float CUTOFF = 5.0f;
constexpr float PI_F = 3.14159265358979323846f;

__device__ __forceinline__ float silu_f(float x) { return x / (1.0f + __expf(-x)); }

// ---------------------------------------------------------------- init: s = emb[Z]
__global__ void init_kernel(const int* __restrict__ Z, const float* __restrict__ emb,
                            float* __restrict__ s) {
    int atom = blockIdx.x;
    int t = threadIdx.x;
    s[atom * F + t] = emb[Z[atom] * F + t];
}

// ---------------------------------------------------------------- bucket edges by dst
__global__ void fill_buckets(const int* __restrict__ eidx, int* __restrict__ count,
                             int* __restrict__ bucket) {
    int e = blockIdx.x * 256 + threadIdx.x;
    if (e >= N_EDGES) return;
    int dst = eidx[2 * e];
    int pos = atomicAdd(&count[dst], 1);
    if (pos < CAP) bucket[dst * CAP + pos] = e;
}

// ---------------------------------------------------------------- transpose all weights
// dst[c*R + r] = src[r*C + c]  (dst layout [C][R]; row c of dst = column c of src)
struct TPlan { const float* src; float* dst; int R, C, blk0; };
struct TPlans { TPlan p[20]; int n; };

__global__ void transpose_all(TPlans P) {
    int b = blockIdx.x;
    int pi = 0;
#pragma unroll
    for (int i = 1; i < 20; ++i)
        if (i < P.n && b >= P.p[i].blk0) pi = i;
    const float* src = P.p[pi].src;
    float* dst = P.p[pi].dst;
    int R = P.p[pi].R, C = P.p[pi].C;
    int f = (b - P.p[pi].blk0) * 256 + threadIdx.x;
    if (f < R * C) {
        int c = f / R, r = f - c * R;
        dst[f] = src[r * C + c];
    }
}

// ---------------------------------------------------------------- phi = silu(s@W1+b1)@W2+b2
// 128 threads (t = out feature), 8 atoms/block, float4 transposed-weight loads
__global__ __launch_bounds__(128) void phi_kernel(
    const float* __restrict__ s, const float* __restrict__ w1T, const float* __restrict__ b1,
    const float* __restrict__ w2T, const float* __restrict__ b2, float* __restrict__ phi) {
    __shared__ __align__(16) float sh_s[F][12];
    __shared__ __align__(16) float sh_h[F][12];
    int a0 = blockIdx.x * 8;
    int t = threadIdx.x;
#pragma unroll
    for (int a = 0; a < 8; ++a) sh_s[t][a] = s[(a0 + a) * F + t];
    __syncthreads();

    float acc[8];
    float bb = b1[t];
#pragma unroll
    for (int a = 0; a < 8; ++a) acc[a] = bb;
    const float* wrow = w1T + t * F;
#pragma unroll 4
    for (int k = 0; k < F; k += 4) {
        float4 wq = *(const float4*)(wrow + k);
        float wj[4] = {wq.x, wq.y, wq.z, wq.w};
#pragma unroll
        for (int j = 0; j < 4; ++j) {
            const float* rp = &sh_s[k + j][0];
            float4 q0 = *(const float4*)rp, q1 = *(const float4*)(rp + 4);
            float sv[8] = {q0.x, q0.y, q0.z, q0.w, q1.x, q1.y, q1.z, q1.w};
#pragma unroll
            for (int a = 0; a < 8; ++a) acc[a] += sv[a] * wj[j];
        }
    }
#pragma unroll
    for (int a = 0; a < 8; ++a) sh_h[t][a] = silu_f(acc[a]);
    __syncthreads();

    float A0[8], A1[8], A2[8];
    float c0 = b2[t], c1 = b2[F + t], c2 = b2[2 * F + t];
#pragma unroll
    for (int a = 0; a < 8; ++a) { A0[a] = c0; A1[a] = c1; A2[a] = c2; }
    const float* r0 = w2T + t * F;
    const float* r1 = w2T + (F + t) * F;
    const float* r2 = w2T + (2 * F + t) * F;
#pragma unroll 4
    for (int k = 0; k < F; k += 4) {
        float4 q0v = *(const float4*)(r0 + k);
        float4 q1v = *(const float4*)(r1 + k);
        float4 q2v = *(const float4*)(r2 + k);
        float w0j[4] = {q0v.x, q0v.y, q0v.z, q0v.w};
        float w1j[4] = {q1v.x, q1v.y, q1v.z, q1v.w};
        float w2j[4] = {q2v.x, q2v.y, q2v.z, q2v.w};
#pragma unroll
        for (int j = 0; j < 4; ++j) {
            const float* rp = &sh_h[k + j][0];
            float4 q0 = *(const float4*)rp, q1 = *(const float4*)(rp + 4);
            float hv[8] = {q0.x, q0.y, q0.z, q0.w, q1.x, q1.y, q1.z, q1.w};
#pragma unroll
            for (int a = 0; a < 8; ++a) {
                A0[a] += hv[a] * w0j[j]; A1[a] += hv[a] * w1j[j]; A2[a] += hv[a] * w2j[j];
            }
        }
    }
#pragma unroll
    for (int a = 0; a < 8; ++a) {
        float* po = phi + (a0 + a) * 3 * F;
        po[t] = A0[a]; po[F + t] = A1[a]; po[2 * F + t] = A2[a];
    }
}

// ---------------------------------------------------------------- per-dst edge aggregation
// software-pipelined gathers: double-buffered groups of 4 edges (round-3 version, kept)
__global__ __launch_bounds__(128) void edge_agg_kernel(
    const int* __restrict__ count, const int* __restrict__ bucket,
    const int* __restrict__ eidx, const float* __restrict__ ediff,
    const float* __restrict__ edist,
    const float* __restrict__ fw, const float* __restrict__ fb,
    const float* __restrict__ phi, const float* __restrict__ v,
    float* __restrict__ ds, float* __restrict__ dv) {
    int a = blockIdx.x;
    int t = threadIdx.x;

    float rfw0[B], rfw1[B], rfw2[B];
#pragma unroll
    for (int b = 0; b < B; ++b) {
        const float* row = fw + b * 3 * F;
        rfw0[b] = row[t]; rfw1[b] = row[F + t]; rfw2[b] = row[2 * F + t];
    }
    float fb0 = fb[t], fb1 = fb[F + t], fb2 = fb[2 * F + t];

    int n = count[a]; if (n > CAP) n = CAP;
    float accS = 0.f, accV0 = 0.f, accV1 = 0.f, accV2 = 0.f;

    __shared__ __align__(16) float sh_rbf[32][B];
    __shared__ float sh_env[32];
    __shared__ float sh_unit[32][3];
    __shared__ int sh_src[32];
    const int* bptr = bucket + a * CAP;

    for (int base = 0; base < n; base += 32) {
        int cnt = min(32, n - base);
        __syncthreads();
        if (t < cnt) {
            int e = bptr[base + t];
            sh_src[t] = eidx[2 * e + 1];
            float d = edist[e];
            float fc = 0.5f * (cosf(PI_F * d / CUTOFF) + 1.0f);
            sh_env[t] = (d < CUTOFF) ? fc : 0.0f;
            float inv = 1.0f / d;
            sh_unit[t][0] = ediff[3 * e + 0] * inv;
            sh_unit[t][1] = ediff[3 * e + 1] * inv;
            sh_unit[t][2] = ediff[3 * e + 2] * inv;
        }
        for (int task = t; task < cnt * B; task += 128) {
            int i = task / B, b = task - i * B;
            int e = bptr[base + i];
            float d = edist[e];
            sh_rbf[i][b] = sinf(d * (float)(b + 1) * (PI_F / CUTOFF)) / d;
        }
        __syncthreads();

        float PA[4][3], VA[4][3], PB[4][3], VB[4][3];
        int ngrp = (cnt + 3) >> 2;

        auto load_grp = [&](int gbase, float P[4][3], float V4[4][3]) {
#pragma unroll
            for (int j = 0; j < 4; ++j) {
                int i = gbase + j;
                int ii = (i < cnt) ? i : (cnt - 1);
                int src = sh_src[ii];
                const float* ps = phi + src * 3 * F;
                const float* vs = v + src * 3 * F;
                P[j][0] = ps[t]; P[j][1] = ps[F + t]; P[j][2] = ps[2 * F + t];
                V4[j][0] = vs[t]; V4[j][1] = vs[F + t]; V4[j][2] = vs[2 * F + t];
            }
        };
        auto comp_grp = [&](int gbase, float P[4][3], float V4[4][3]) {
#pragma unroll
            for (int j = 0; j < 4; ++j) {
                int i = gbase + j;
                if (i < cnt) {
                    float f0 = fb0, f1 = fb1, f2 = fb2;
#pragma unroll
                    for (int b = 0; b < B; ++b) {
                        float r = sh_rbf[i][b];
                        f0 += r * rfw0[b]; f1 += r * rfw1[b]; f2 += r * rfw2[b];
                    }
                    float env = sh_env[i];
                    f0 *= env; f1 *= env; f2 *= env;
                    accS += f2 * P[j][2];
                    float gsv = f0 * P[j][0], gev = f1 * P[j][1];
                    accV0 += V4[j][0] * gsv + gev * sh_unit[i][0];
                    accV1 += V4[j][1] * gsv + gev * sh_unit[i][1];
                    accV2 += V4[j][2] * gsv + gev * sh_unit[i][2];
                }
            }
        };

        load_grp(0, PA, VA);
        for (int g = 0; g < ngrp; g += 2) {
            if (g + 1 < ngrp) load_grp((g + 1) * 4, PB, VB);
            comp_grp(g * 4, PA, VA);
            if (g + 1 < ngrp) {
                if (g + 2 < ngrp) load_grp((g + 2) * 4, PA, VA);
                comp_grp((g + 1) * 4, PB, VB);
            }
        }
    }
    ds[a * F + t] = accS;
    float* dvd = dv + a * 3 * F;
    dvd[t] = accV0; dvd[F + t] = accV1; dvd[2 * F + t] = accV2;
}

// ---------------------------------------------------------------- per-atom update
// 128 threads, 8 atoms/thread (round-2 ILP), float4 transposed-weight loads
__global__ __launch_bounds__(128) void update_kernel(
    float* __restrict__ s, float* __restrict__ v,
    const float* __restrict__ ds, const float* __restrict__ dv,
    const float* __restrict__ UT, const float* __restrict__ VT,
    const float* __restrict__ w1T,  // [F][2F]: row t = column t of upd_w1
    const float* __restrict__ b1,
    const float* __restrict__ w2T,  // [3F][F]
    const float* __restrict__ b2) {
    __shared__ __align__(16) float sh_s[F][12];
    __shared__ __align__(16) float sh_vn[F][12];
    __shared__ __align__(16) float sh_h[F][12];
    __shared__ __align__(16) float sh_v[3][F][12];
    int a0 = blockIdx.x * 8;
    int t = threadIdx.x;
    float sn[8];
#pragma unroll
    for (int a = 0; a < 8; ++a) {
        int atom = a0 + a;
        sn[a] = s[atom * F + t] + ds[atom * F + t];
        sh_s[t][a] = sn[a];
#pragma unroll
        for (int d = 0; d < 3; ++d)
            sh_v[d][t][a] = v[atom * 3 * F + d * F + t] + dv[atom * 3 * F + d * F + t];
    }
    __syncthreads();

    float uv[3][8], vv[3][8];
#pragma unroll
    for (int d = 0; d < 3; ++d)
#pragma unroll
        for (int a = 0; a < 8; ++a) { uv[d][a] = 0.f; vv[d][a] = 0.f; }
    const float* ur = UT + t * F;
    const float* vr = VT + t * F;
#pragma unroll 2
    for (int k = 0; k < F; k += 4) {
        float4 uq = *(const float4*)(ur + k);
        float4 vq = *(const float4*)(vr + k);
        float uj[4] = {uq.x, uq.y, uq.z, uq.w};
        float vj[4] = {vq.x, vq.y, vq.z, vq.w};
#pragma unroll
        for (int j = 0; j < 4; ++j) {
#pragma unroll
            for (int d = 0; d < 3; ++d) {
                const float* rp = &sh_v[d][k + j][0];
                float4 q0 = *(const float4*)rp, q1 = *(const float4*)(rp + 4);
                float xv[8] = {q0.x, q0.y, q0.z, q0.w, q1.x, q1.y, q1.z, q1.w};
#pragma unroll
                for (int a = 0; a < 8; ++a) {
                    uv[d][a] += xv[a] * uj[j]; vv[d][a] += xv[a] * vj[j];
                }
            }
        }
    }
#pragma unroll
    for (int a = 0; a < 8; ++a)
        sh_vn[t][a] = sqrtf(vv[0][a] * vv[0][a] + vv[1][a] * vv[1][a] + vv[2][a] * vv[2][a]);
    __syncthreads();

    float hh[8];
    float bb = b1[t];
#pragma unroll
    for (int a = 0; a < 8; ++a) hh[a] = bb;
    const float* ar = w1T + t * 2 * F;   // [0..128) -> s part, [128..256) -> vn part
#pragma unroll 2
    for (int k = 0; k < F; k += 4) {
        float4 wa = *(const float4*)(ar + k);
        float4 wb = *(const float4*)(ar + F + k);
        float waj[4] = {wa.x, wa.y, wa.z, wa.w};
        float wbj[4] = {wb.x, wb.y, wb.z, wb.w};
#pragma unroll
        for (int j = 0; j < 4; ++j) {
            const float* rs = &sh_s[k + j][0];
            const float* rn = &sh_vn[k + j][0];
            float4 s0 = *(const float4*)rs, s1 = *(const float4*)(rs + 4);
            float4 n0 = *(const float4*)rn, n1 = *(const float4*)(rn + 4);
            float svv[8] = {s0.x, s0.y, s0.z, s0.w, s1.x, s1.y, s1.z, s1.w};
            float nvv[8] = {n0.x, n0.y, n0.z, n0.w, n1.x, n1.y, n1.z, n1.w};
#pragma unroll
            for (int a = 0; a < 8; ++a) hh[a] += svv[a] * waj[j] + nvv[a] * wbj[j];
        }
    }
#pragma unroll
    for (int a = 0; a < 8; ++a) sh_h[t][a] = silu_f(hh[a]);
    __syncthreads();

    float A0[8], A1[8], A2[8];
    float c0 = b2[t], c1 = b2[F + t], c2 = b2[2 * F + t];
#pragma unroll
    for (int a = 0; a < 8; ++a) { A0[a] = c0; A1[a] = c1; A2[a] = c2; }
    const float* r0 = w2T + t * F;
    const float* r1 = w2T + (F + t) * F;
    const float* r2 = w2T + (2 * F + t) * F;
#pragma unroll 2
    for (int k = 0; k < F; k += 4) {
        float4 q0v = *(const float4*)(r0 + k);
        float4 q1v = *(const float4*)(r1 + k);
        float4 q2v = *(const float4*)(r2 + k);
        float w0j[4] = {q0v.x, q0v.y, q0v.z, q0v.w};
        float w1j[4] = {q1v.x, q1v.y, q1v.z, q1v.w};
        float w2j[4] = {q2v.x, q2v.y, q2v.z, q2v.w};
#pragma unroll
        for (int j = 0; j < 4; ++j) {
            const float* rp = &sh_h[k + j][0];
            float4 q0 = *(const float4*)rp, q1 = *(const float4*)(rp + 4);
            float hv[8] = {q0.x, q0.y, q0.z, q0.w, q1.x, q1.y, q1.z, q1.w};
#pragma unroll
            for (int a = 0; a < 8; ++a) {
                A0[a] += hv[a] * w0j[j]; A1[a] += hv[a] * w1j[j]; A2[a] += hv[a] * w2j[j];
            }
        }
    }
#pragma unroll
    for (int a = 0; a < 8; ++a) {
        int atom = a0 + a;
        float dot = uv[0][a] * vv[0][a] + uv[1][a] * vv[1][a] + uv[2][a] * vv[2][a];
#pragma unroll
        for (int d = 0; d < 3; ++d)
            v[atom * 3 * F + d * F + t] = sh_v[d][t][a] + A0[a] * uv[d][a];
        s[atom * F + t] = sn[a] + A1[a] * dot + A2[a];
    }
}

// ---------------------------------------------------------------- readout, 16 atoms/block, 64 threads
__global__ __launch_bounds__(64) void readout_kernel(
    const float* __restrict__ s, const float* __restrict__ w1T,  // [64][F]
    const float* __restrict__ b1,
    const float* __restrict__ w2, const float* __restrict__ b2, float* __restrict__ out) {
    const int TA = 16;
    __shared__ __align__(16) float sh_s[F][20];
    int a0 = blockIdx.x * TA;
    int t = threadIdx.x;  // 0..63
#pragma unroll
    for (int a = 0; a < TA; ++a) {
        int atom = a0 + a;
        sh_s[t][a]      = (atom < N_ATOMS) ? s[atom * F + t] : 0.0f;
        sh_s[t + 64][a] = (atom < N_ATOMS) ? s[atom * F + 64 + t] : 0.0f;
    }
    __syncthreads();
    float acc[TA];
    float bb = b1[t];
#pragma unroll
    for (int a = 0; a < TA; ++a) acc[a] = bb;
    const float* wr = w1T + t * F;
#pragma unroll 2
    for (int k = 0; k < F; k += 4) {
        float4 wq = *(const float4*)(wr + k);
        float wj[4] = {wq.x, wq.y, wq.z, wq.w};
#pragma unroll
        for (int j = 0; j < 4; ++j) {
            const float* rp = &sh_s[k + j][0];
            float4 q0 = *(const float4*)(rp), q1 = *(const float4*)(rp + 4);
            float4 q2 = *(const float4*)(rp + 8), q3 = *(const float4*)(rp + 12);
            float sv[TA] = {q0.x, q0.y, q0.z, q0.w, q1.x, q1.y, q1.z, q1.w,
                            q2.x, q2.y, q2.z, q2.w, q3.x, q3.y, q3.z, q3.w};
#pragma unroll
            for (int a = 0; a < TA; ++a) acc[a] += sv[a] * wj[j];
        }
    }
    float w2t = w2[t];
    float p[TA];
#pragma unroll
    for (int a = 0; a < TA; ++a) p[a] = silu_f(acc[a]) * w2t;
#pragma unroll
    for (int a = 0; a < TA; ++a)
#pragma unroll
        for (int off = 32; off > 0; off >>= 1) p[a] += __shfl_down(p[a], off, 64);
    if (t == 0) {
        float bias = b2[0];
#pragma unroll
        for (int a = 0; a < TA; ++a) {
            int atom = a0 + a;
            if (atom < N_ATOMS) out[atom] = p[a] + bias;
        }
    }
}

extern "C" void kernel_launch(void* const* d_in, const int* in_sizes, int n_in,
                              void* d_out, int out_size, void* d_ws, size_t ws_size,
                              hipStream_t stream) {
    const int*   Z      = (const int*)d_in[0];
    const int*   eidx   = (const int*)d_in[1];
    const float* ediff  = (const float*)d_in[2];
    const float* edist  = (const float*)d_in[3];
    const float* emb    = (const float*)d_in[4];
    const float* msg_w1 = (const float*)d_in[5];
    const float* msg_b1 = (const float*)d_in[6];
    const float* msg_w2 = (const float*)d_in[7];
    const float* msg_b2 = (const float*)d_in[8];
    const float* filt_w = (const float*)d_in[9];
    const float* filt_b = (const float*)d_in[10];
    const float* upd_U  = (const float*)d_in[11];
    const float* upd_V  = (const float*)d_in[12];
    const float* upd_w1 = (const float*)d_in[13];
    const float* upd_b1 = (const float*)d_in[14];
    const float* upd_w2 = (const float*)d_in[15];
    const float* upd_b2 = (const float*)d_in[16];
    const float* ro_w1  = (const float*)d_in[17];
    const float* ro_b1  = (const float*)d_in[18];
    const float* ro_w2  = (const float*)d_in[19];
    const float* ro_b2  = (const float*)d_in[20];
    float* out = (float*)d_out;

    float* ws  = (float*)d_ws;
    float* s    = ws;                     // N*F
    float* v    = s + N_ATOMS * F;        // N*3F
    float* phi  = v + N_ATOMS * 3 * F;    // N*3F
    float* ds   = phi + N_ATOMS * 3 * F;  // N*F
    float* dv   = ds + N_ATOMS * F;       // N*3F
    int* count  = (int*)(dv + N_ATOMS * 3 * F);  // N
    int* bucket = count + N_ATOMS;               // N*CAP
    float* wT   = (float*)(bucket + N_ATOMS * CAP);

    // transposed weight layout per layer
    const int L_W1T = F * F, L_W2T = F * 3 * F, L_UT = F * F, L_VT = F * F,
              L_UW1T = 2 * F * F, L_UW2T = F * 3 * F;
    const int LAYER_T = L_W1T + L_W2T + L_UT + L_VT + L_UW1T + L_UW2T;
    float* w1T_base  = wT;
    float* w2T_base  = wT + L_W1T;
    float* UT_base   = wT + L_W1T + L_W2T;
    float* VT_base   = wT + L_W1T + L_W2T + L_UT;
    float* uw1T_base = wT + L_W1T + L_W2T + L_UT + L_VT;
    float* uw2T_base = wT + L_W1T + L_W2T + L_UT + L_VT + L_UW1T;
    float* roT       = wT + (size_t)NL * LAYER_T;   // [64][F]

    TPlans P;
    int nb = 0, pi = 0;
    auto add = [&](const float* src, float* dst, int R, int C) {
        P.p[pi].src = src; P.p[pi].dst = dst; P.p[pi].R = R; P.p[pi].C = C;
        P.p[pi].blk0 = nb;
        nb += (R * C + 255) / 256; ++pi;
    };
    for (int l = 0; l < NL; ++l) {
        add(msg_w1 + l * F * F,     w1T_base  + l * LAYER_T, F, F);
        add(msg_w2 + l * F * 3 * F, w2T_base  + l * LAYER_T, F, 3 * F);
        add(upd_U  + l * F * F,     UT_base   + l * LAYER_T, F, F);
        add(upd_V  + l * F * F,     VT_base   + l * LAYER_T, F, F);
        add(upd_w1 + l * 2 * F * F, uw1T_base + l * LAYER_T, 2 * F, F);
        add(upd_w2 + l * F * 3 * F, uw2T_base + l * LAYER_T, F, 3 * F);
    }
    add(ro_w1, roT, F, 64);
    P.n = pi;

    init_kernel<<<N_ATOMS, F, 0, stream>>>(Z, emb, s);
    hipMemsetAsync(v, 0, (size_t)N_ATOMS * 3 * F * sizeof(float), stream);
    hipMemsetAsync(count, 0, (size_t)N_ATOMS * sizeof(int), stream);
    fill_buckets<<<(N_EDGES + 255) / 256, 256, 0, stream>>>(eidx, count, bucket);
    transpose_all<<<nb, 256, 0, stream>>>(P);

    for (int l = 0; l < NL; ++l) {
        phi_kernel<<<N_ATOMS / 8, 128, 0, stream>>>(
            s, w1T_base + l * LAYER_T, msg_b1 + l * F,
            w2T_base + l * LAYER_T, msg_b2 + l * 3 * F, phi);
        edge_agg_kernel<<<N_ATOMS, 128, 0, stream>>>(
            count, bucket, eidx, ediff, edist,
            filt_w + l * B * 3 * F, filt_b + l * 3 * F, phi, v, ds, dv);
        update_kernel<<<N_ATOMS / 8, 128, 0, stream>>>(
            s, v, ds, dv, UT_base + l * LAYER_T, VT_base + l * LAYER_T,
            uw1T_base + l * LAYER_T, upd_b1 + l * F,
            uw2T_base + l * LAYER_T, upd_b2 + l * 3 * F);
    }
    readout_kernel<<<(N_ATOMS + 15) / 16, 64, 0, stream>>>(s, roT, ro_b1, ro_w2, ro_b2, out);
}

// Round 5
// 569.297 us; speedup vs baseline: 1.1792x; 1.0715x over previous
//
#include <hip/hip_runtime.h>
#include <hip/hip_bf16.h>
#include <hip/hip_fp16.h>
#include <math.h>

#define N_ATOMS 5000
#define N_EDGES 100000
#define F 128
#define B 20
#define NL 3
#define CAP 96

constexpr float CUTOFF = 5.0f;
constexpr float PI_F = 3.14159265358979323846f;

__device__ __forceinline__ float silu_f(float x) { return x / (1.0f + __expf(-x)); }

// ---------------------------------------------------------------- init: s = emb[Z]
__global__ void init_kernel(const int* __restrict__ Z, const float* __restrict__ emb,
                            float* __restrict__ s) {
    int atom = blockIdx.x;
    int t = threadIdx.x;
    s[atom * F + t] = emb[Z[atom] * F + t];
}

// ---------------------------------------------------------------- bucket edges by dst
__global__ void fill_buckets(const int* __restrict__ eidx, int* __restrict__ count,
                             int* __restrict__ bucket) {
    int e = blockIdx.x * 256 + threadIdx.x;
    if (e >= N_EDGES) return;
    int dst = eidx[2 * e];
    int pos = atomicAdd(&count[dst], 1);
    if (pos < CAP) bucket[dst * CAP + pos] = e;
}

// ---------------------------------------------------------------- transpose all weights
struct TPlan { const float* src; float* dst; int R, C, blk0; };
struct TPlans { TPlan p[20]; int n; };

__global__ void transpose_all(TPlans P) {
    int b = blockIdx.x;
    int pi = 0;
#pragma unroll
    for (int i = 1; i < 20; ++i)
        if (i < P.n && b >= P.p[i].blk0) pi = i;
    const float* src = P.p[pi].src;
    float* dst = P.p[pi].dst;
    int R = P.p[pi].R, C = P.p[pi].C;
    int f = (b - P.p[pi].blk0) * 256 + threadIdx.x;
    if (f < R * C) {
        int c = f / R, r = f - c * R;
        dst[f] = src[r * C + c];
    }
}

// ---------------------------------------------------------------- phi = silu(s@W1+b1)@W2+b2
// 128 threads (t = out feature), 8 atoms/block; OUTPUT IS HALF (consumed only by edge_agg)
__global__ __launch_bounds__(128) void phi_kernel(
    const float* __restrict__ s, const float* __restrict__ w1T, const float* __restrict__ b1,
    const float* __restrict__ w2T, const float* __restrict__ b2, __half* __restrict__ phi_h) {
    __shared__ __align__(16) float sh_s[F][12];
    __shared__ __align__(16) float sh_h[F][12];
    int a0 = blockIdx.x * 8;
    int t = threadIdx.x;
#pragma unroll
    for (int a = 0; a < 8; ++a) sh_s[t][a] = s[(a0 + a) * F + t];
    __syncthreads();

    float acc[8];
    float bb = b1[t];
#pragma unroll
    for (int a = 0; a < 8; ++a) acc[a] = bb;
    const float* wrow = w1T + t * F;
#pragma unroll 4
    for (int k = 0; k < F; k += 4) {
        float4 wq = *(const float4*)(wrow + k);
        float wj[4] = {wq.x, wq.y, wq.z, wq.w};
#pragma unroll
        for (int j = 0; j < 4; ++j) {
            const float* rp = &sh_s[k + j][0];
            float4 q0 = *(const float4*)rp, q1 = *(const float4*)(rp + 4);
            float sv[8] = {q0.x, q0.y, q0.z, q0.w, q1.x, q1.y, q1.z, q1.w};
#pragma unroll
            for (int a = 0; a < 8; ++a) acc[a] += sv[a] * wj[j];
        }
    }
#pragma unroll
    for (int a = 0; a < 8; ++a) sh_h[t][a] = silu_f(acc[a]);
    __syncthreads();

    float A0[8], A1[8], A2[8];
    float c0 = b2[t], c1 = b2[F + t], c2 = b2[2 * F + t];
#pragma unroll
    for (int a = 0; a < 8; ++a) { A0[a] = c0; A1[a] = c1; A2[a] = c2; }
    const float* r0 = w2T + t * F;
    const float* r1 = w2T + (F + t) * F;
    const float* r2 = w2T + (2 * F + t) * F;
#pragma unroll 4
    for (int k = 0; k < F; k += 4) {
        float4 q0v = *(const float4*)(r0 + k);
        float4 q1v = *(const float4*)(r1 + k);
        float4 q2v = *(const float4*)(r2 + k);
        float w0j[4] = {q0v.x, q0v.y, q0v.z, q0v.w};
        float w1j[4] = {q1v.x, q1v.y, q1v.z, q1v.w};
        float w2j[4] = {q2v.x, q2v.y, q2v.z, q2v.w};
#pragma unroll
        for (int j = 0; j < 4; ++j) {
            const float* rp = &sh_h[k + j][0];
            float4 q0 = *(const float4*)rp, q1 = *(const float4*)(rp + 4);
            float hv[8] = {q0.x, q0.y, q0.z, q0.w, q1.x, q1.y, q1.z, q1.w};
#pragma unroll
            for (int a = 0; a < 8; ++a) {
                A0[a] += hv[a] * w0j[j]; A1[a] += hv[a] * w1j[j]; A2[a] += hv[a] * w2j[j];
            }
        }
    }
#pragma unroll
    for (int a = 0; a < 8; ++a) {
        __half* po = phi_h + (size_t)(a0 + a) * 3 * F;
        po[t] = __float2half(A0[a]);
        po[F + t] = __float2half(A1[a]);
        po[2 * F + t] = __float2half(A2[a]);
    }
}

// ---------------------------------------------------------------- per-dst edge aggregation
// fp16 gathers of phi/v (half the bytes), software-pipelined groups of 4 edges
__global__ __launch_bounds__(128) void edge_agg_kernel(
    const int* __restrict__ count, const int* __restrict__ bucket,
    const int* __restrict__ eidx, const float* __restrict__ ediff,
    const float* __restrict__ edist,
    const float* __restrict__ fw, const float* __restrict__ fb,
    const __half* __restrict__ phi_h, const __half* __restrict__ v_h,
    float* __restrict__ ds, float* __restrict__ dv) {
    int a = blockIdx.x;
    int t = threadIdx.x;

    float rfw0[B], rfw1[B], rfw2[B];
#pragma unroll
    for (int b = 0; b < B; ++b) {
        const float* row = fw + b * 3 * F;
        rfw0[b] = row[t]; rfw1[b] = row[F + t]; rfw2[b] = row[2 * F + t];
    }
    float fb0 = fb[t], fb1 = fb[F + t], fb2 = fb[2 * F + t];

    int n = count[a]; if (n > CAP) n = CAP;
    float accS = 0.f, accV0 = 0.f, accV1 = 0.f, accV2 = 0.f;

    __shared__ __align__(16) float sh_rbf[32][B];
    __shared__ float sh_env[32];
    __shared__ float sh_unit[32][3];
    __shared__ int sh_src[32];
    const int* bptr = bucket + a * CAP;

    for (int base = 0; base < n; base += 32) {
        int cnt = min(32, n - base);
        __syncthreads();
        if (t < cnt) {
            int e = bptr[base + t];
            sh_src[t] = eidx[2 * e + 1];
            float d = edist[e];
            float fc = 0.5f * (cosf(PI_F * d / CUTOFF) + 1.0f);
            sh_env[t] = (d < CUTOFF) ? fc : 0.0f;
            float inv = 1.0f / d;
            sh_unit[t][0] = ediff[3 * e + 0] * inv;
            sh_unit[t][1] = ediff[3 * e + 1] * inv;
            sh_unit[t][2] = ediff[3 * e + 2] * inv;
        }
        for (int task = t; task < cnt * B; task += 128) {
            int i = task / B, b = task - i * B;
            int e = bptr[base + i];
            float d = edist[e];
            sh_rbf[i][b] = sinf(d * (float)(b + 1) * (PI_F / CUTOFF)) / d;
        }
        __syncthreads();

        __half PA[4][3], VA[4][3], PB[4][3], VB[4][3];
        int ngrp = (cnt + 3) >> 2;

        auto load_grp = [&](int gbase, __half P[4][3], __half V4[4][3]) {
#pragma unroll
            for (int j = 0; j < 4; ++j) {
                int i = gbase + j;
                int ii = (i < cnt) ? i : (cnt - 1);
                int src = sh_src[ii];
                const __half* ps = phi_h + (size_t)src * 3 * F;
                const __half* vs = v_h + (size_t)src * 3 * F;
                P[j][0] = ps[t]; P[j][1] = ps[F + t]; P[j][2] = ps[2 * F + t];
                V4[j][0] = vs[t]; V4[j][1] = vs[F + t]; V4[j][2] = vs[2 * F + t];
            }
        };
        auto comp_grp = [&](int gbase, __half P[4][3], __half V4[4][3]) {
#pragma unroll
            for (int j = 0; j < 4; ++j) {
                int i = gbase + j;
                if (i < cnt) {
                    float f0 = fb0, f1 = fb1, f2 = fb2;
#pragma unroll
                    for (int b = 0; b < B; ++b) {
                        float r = sh_rbf[i][b];
                        f0 += r * rfw0[b]; f1 += r * rfw1[b]; f2 += r * rfw2[b];
                    }
                    float env = sh_env[i];
                    f0 *= env; f1 *= env; f2 *= env;
                    accS += f2 * __half2float(P[j][2]);
                    float gsv = f0 * __half2float(P[j][0]);
                    float gev = f1 * __half2float(P[j][1]);
                    accV0 += __half2float(V4[j][0]) * gsv + gev * sh_unit[i][0];
                    accV1 += __half2float(V4[j][1]) * gsv + gev * sh_unit[i][1];
                    accV2 += __half2float(V4[j][2]) * gsv + gev * sh_unit[i][2];
                }
            }
        };

        load_grp(0, PA, VA);
        for (int g = 0; g < ngrp; g += 2) {
            if (g + 1 < ngrp) load_grp((g + 1) * 4, PB, VB);
            comp_grp(g * 4, PA, VA);
            if (g + 1 < ngrp) {
                if (g + 2 < ngrp) load_grp((g + 2) * 4, PA, VA);
                comp_grp((g + 1) * 4, PB, VB);
            }
        }
    }
    ds[a * F + t] = accS;
    float* dvd = dv + a * 3 * F;
    dvd[t] = accV0; dvd[F + t] = accV1; dvd[2 * F + t] = accV2;
}

// ---------------------------------------------------------------- per-atom update
// 128 threads, 8 atoms/block; writes fp32 v AND half shadow v_h for next layer's gathers
__global__ __launch_bounds__(128) void update_kernel(
    float* __restrict__ s, float* __restrict__ v, __half* __restrict__ v_h,
    const float* __restrict__ ds, const float* __restrict__ dv,
    const float* __restrict__ UT, const float* __restrict__ VT,
    const float* __restrict__ w1T, const float* __restrict__ b1,
    const float* __restrict__ w2T, const float* __restrict__ b2) {
    __shared__ __align__(16) float sh_s[F][12];
    __shared__ __align__(16) float sh_vn[F][12];
    __shared__ __align__(16) float sh_h[F][12];
    __shared__ __align__(16) float sh_v[3][F][12];
    int a0 = blockIdx.x * 8;
    int t = threadIdx.x;
    float sn[8];
#pragma unroll
    for (int a = 0; a < 8; ++a) {
        int atom = a0 + a;
        sn[a] = s[atom * F + t] + ds[atom * F + t];
        sh_s[t][a] = sn[a];
#pragma unroll
        for (int d = 0; d < 3; ++d)
            sh_v[d][t][a] = v[atom * 3 * F + d * F + t] + dv[atom * 3 * F + d * F + t];
    }
    __syncthreads();

    float uv[3][8], vv[3][8];
#pragma unroll
    for (int d = 0; d < 3; ++d)
#pragma unroll
        for (int a = 0; a < 8; ++a) { uv[d][a] = 0.f; vv[d][a] = 0.f; }
    const float* ur = UT + t * F;
    const float* vr = VT + t * F;
#pragma unroll 2
    for (int k = 0; k < F; k += 4) {
        float4 uq = *(const float4*)(ur + k);
        float4 vq = *(const float4*)(vr + k);
        float uj[4] = {uq.x, uq.y, uq.z, uq.w};
        float vj[4] = {vq.x, vq.y, vq.z, vq.w};
#pragma unroll
        for (int j = 0; j < 4; ++j) {
#pragma unroll
            for (int d = 0; d < 3; ++d) {
                const float* rp = &sh_v[d][k + j][0];
                float4 q0 = *(const float4*)rp, q1 = *(const float4*)(rp + 4);
                float xv[8] = {q0.x, q0.y, q0.z, q0.w, q1.x, q1.y, q1.z, q1.w};
#pragma unroll
                for (int a = 0; a < 8; ++a) {
                    uv[d][a] += xv[a] * uj[j]; vv[d][a] += xv[a] * vj[j];
                }
            }
        }
    }
#pragma unroll
    for (int a = 0; a < 8; ++a)
        sh_vn[t][a] = sqrtf(vv[0][a] * vv[0][a] + vv[1][a] * vv[1][a] + vv[2][a] * vv[2][a]);
    __syncthreads();

    float hh[8];
    float bb = b1[t];
#pragma unroll
    for (int a = 0; a < 8; ++a) hh[a] = bb;
    const float* ar = w1T + t * 2 * F;
#pragma unroll 2
    for (int k = 0; k < F; k += 4) {
        float4 wa = *(const float4*)(ar + k);
        float4 wb = *(const float4*)(ar + F + k);
        float waj[4] = {wa.x, wa.y, wa.z, wa.w};
        float wbj[4] = {wb.x, wb.y, wb.z, wb.w};
#pragma unroll
        for (int j = 0; j < 4; ++j) {
            const float* rs = &sh_s[k + j][0];
            const float* rn = &sh_vn[k + j][0];
            float4 s0 = *(const float4*)rs, s1 = *(const float4*)(rs + 4);
            float4 n0 = *(const float4*)rn, n1 = *(const float4*)(rn + 4);
            float svv[8] = {s0.x, s0.y, s0.z, s0.w, s1.x, s1.y, s1.z, s1.w};
            float nvv[8] = {n0.x, n0.y, n0.z, n0.w, n1.x, n1.y, n1.z, n1.w};
#pragma unroll
            for (int a = 0; a < 8; ++a) hh[a] += svv[a] * waj[j] + nvv[a] * wbj[j];
        }
    }
#pragma unroll
    for (int a = 0; a < 8; ++a) sh_h[t][a] = silu_f(hh[a]);
    __syncthreads();

    float A0[8], A1[8], A2[8];
    float c0 = b2[t], c1 = b2[F + t], c2 = b2[2 * F + t];
#pragma unroll
    for (int a = 0; a < 8; ++a) { A0[a] = c0; A1[a] = c1; A2[a] = c2; }
    const float* r0 = w2T + t * F;
    const float* r1 = w2T + (F + t) * F;
    const float* r2 = w2T + (2 * F + t) * F;
#pragma unroll 2
    for (int k = 0; k < F; k += 4) {
        float4 q0v = *(const float4*)(r0 + k);
        float4 q1v = *(const float4*)(r1 + k);
        float4 q2v = *(const float4*)(r2 + k);
        float w0j[4] = {q0v.x, q0v.y, q0v.z, q0v.w};
        float w1j[4] = {q1v.x, q1v.y, q1v.z, q1v.w};
        float w2j[4] = {q2v.x, q2v.y, q2v.z, q2v.w};
#pragma unroll
        for (int j = 0; j < 4; ++j) {
            const float* rp = &sh_h[k + j][0];
            float4 q0 = *(const float4*)rp, q1 = *(const float4*)(rp + 4);
            float hv[8] = {q0.x, q0.y, q0.z, q0.w, q1.x, q1.y, q1.z, q1.w};
#pragma unroll
            for (int a = 0; a < 8; ++a) {
                A0[a] += hv[a] * w0j[j]; A1[a] += hv[a] * w1j[j]; A2[a] += hv[a] * w2j[j];
            }
        }
    }
#pragma unroll
    for (int a = 0; a < 8; ++a) {
        int atom = a0 + a;
        float dot = uv[0][a] * vv[0][a] + uv[1][a] * vv[1][a] + uv[2][a] * vv[2][a];
#pragma unroll
        for (int d = 0; d < 3; ++d) {
            float nv = sh_v[d][t][a] + A0[a] * uv[d][a];
            v[atom * 3 * F + d * F + t] = nv;
            v_h[(size_t)atom * 3 * F + d * F + t] = __float2half(nv);
        }
        s[atom * F + t] = sn[a] + A1[a] * dot + A2[a];
    }
}

// ---------------------------------------------------------------- readout, 16 atoms/block, 64 threads
__global__ __launch_bounds__(64) void readout_kernel(
    const float* __restrict__ s, const float* __restrict__ w1T,
    const float* __restrict__ b1,
    const float* __restrict__ w2, const float* __restrict__ b2, float* __restrict__ out) {
    const int TA = 16;
    __shared__ __align__(16) float sh_s[F][20];
    int a0 = blockIdx.x * TA;
    int t = threadIdx.x;
#pragma unroll
    for (int a = 0; a < TA; ++a) {
        int atom = a0 + a;
        sh_s[t][a]      = (atom < N_ATOMS) ? s[atom * F + t] : 0.0f;
        sh_s[t + 64][a] = (atom < N_ATOMS) ? s[atom * F + 64 + t] : 0.0f;
    }
    __syncthreads();
    float acc[TA];
    float bb = b1[t];
#pragma unroll
    for (int a = 0; a < TA; ++a) acc[a] = bb;
    const float* wr = w1T + t * F;
#pragma unroll 2
    for (int k = 0; k < F; k += 4) {
        float4 wq = *(const float4*)(wr + k);
        float wj[4] = {wq.x, wq.y, wq.z, wq.w};
#pragma unroll
        for (int j = 0; j < 4; ++j) {
            const float* rp = &sh_s[k + j][0];
            float4 q0 = *(const float4*)(rp), q1 = *(const float4*)(rp + 4);
            float4 q2 = *(const float4*)(rp + 8), q3 = *(const float4*)(rp + 12);
            float sv[TA] = {q0.x, q0.y, q0.z, q0.w, q1.x, q1.y, q1.z, q1.w,
                            q2.x, q2.y, q2.z, q2.w, q3.x, q3.y, q3.z, q3.w};
#pragma unroll
            for (int a = 0; a < TA; ++a) acc[a] += sv[a] * wj[j];
        }
    }
    float w2t = w2[t];
    float p[TA];
#pragma unroll
    for (int a = 0; a < TA; ++a) p[a] = silu_f(acc[a]) * w2t;
#pragma unroll
    for (int a = 0; a < TA; ++a)
#pragma unroll
        for (int off = 32; off > 0; off >>= 1) p[a] += __shfl_down(p[a], off, 64);
    if (t == 0) {
        float bias = b2[0];
#pragma unroll
        for (int a = 0; a < TA; ++a) {
            int atom = a0 + a;
            if (atom < N_ATOMS) out[atom] = p[a] + bias;
        }
    }
}

extern "C" void kernel_launch(void* const* d_in, const int* in_sizes, int n_in,
                              void* d_out, int out_size, void* d_ws, size_t ws_size,
                              hipStream_t stream) {
    const int*   Z      = (const int*)d_in[0];
    const int*   eidx   = (const int*)d_in[1];
    const float* ediff  = (const float*)d_in[2];
    const float* edist  = (const float*)d_in[3];
    const float* emb    = (const float*)d_in[4];
    const float* msg_w1 = (const float*)d_in[5];
    const float* msg_b1 = (const float*)d_in[6];
    const float* msg_w2 = (const float*)d_in[7];
    const float* msg_b2 = (const float*)d_in[8];
    const float* filt_w = (const float*)d_in[9];
    const float* filt_b = (const float*)d_in[10];
    const float* upd_U  = (const float*)d_in[11];
    const float* upd_V  = (const float*)d_in[12];
    const float* upd_w1 = (const float*)d_in[13];
    const float* upd_b1 = (const float*)d_in[14];
    const float* upd_w2 = (const float*)d_in[15];
    const float* upd_b2 = (const float*)d_in[16];
    const float* ro_w1  = (const float*)d_in[17];
    const float* ro_b1  = (const float*)d_in[18];
    const float* ro_w2  = (const float*)d_in[19];
    const float* ro_b2  = (const float*)d_in[20];
    float* out = (float*)d_out;

    float* ws  = (float*)d_ws;
    float* s    = ws;                     // N*F fp32
    float* v    = s + N_ATOMS * F;        // N*3F fp32
    float* ds   = v + N_ATOMS * 3 * F;    // N*F fp32
    float* dv   = ds + N_ATOMS * F;       // N*3F fp32
    int* count  = (int*)(dv + N_ATOMS * 3 * F);  // N
    int* bucket = count + N_ATOMS;               // N*CAP
    float* wT   = (float*)(bucket + N_ATOMS * CAP);

    const int L_W1T = F * F, L_W2T = F * 3 * F, L_UT = F * F, L_VT = F * F,
              L_UW1T = 2 * F * F, L_UW2T = F * 3 * F;
    const int LAYER_T = L_W1T + L_W2T + L_UT + L_VT + L_UW1T + L_UW2T;
    float* w1T_base  = wT;
    float* w2T_base  = wT + L_W1T;
    float* UT_base   = wT + L_W1T + L_W2T;
    float* VT_base   = wT + L_W1T + L_W2T + L_UT;
    float* uw1T_base = wT + L_W1T + L_W2T + L_UT + L_VT;
    float* uw2T_base = wT + L_W1T + L_W2T + L_UT + L_VT + L_UW1T;
    float* roT       = wT + (size_t)NL * LAYER_T;   // [64][F]
    // half buffers after the fp32/int region
    __half* phi_h = (__half*)(roT + F * 64);            // N*3F half
    __half* v_h   = phi_h + (size_t)N_ATOMS * 3 * F;    // N*3F half

    TPlans P;
    int nb = 0, pi = 0;
    auto add = [&](const float* src, float* dst, int R, int C) {
        P.p[pi].src = src; P.p[pi].dst = dst; P.p[pi].R = R; P.p[pi].C = C;
        P.p[pi].blk0 = nb;
        nb += (R * C + 255) / 256; ++pi;
    };
    for (int l = 0; l < NL; ++l) {
        add(msg_w1 + l * F * F,     w1T_base  + l * LAYER_T, F, F);
        add(msg_w2 + l * F * 3 * F, w2T_base  + l * LAYER_T, F, 3 * F);
        add(upd_U  + l * F * F,     UT_base   + l * LAYER_T, F, F);
        add(upd_V  + l * F * F,     VT_base   + l * LAYER_T, F, F);
        add(upd_w1 + l * 2 * F * F, uw1T_base + l * LAYER_T, 2 * F, F);
        add(upd_w2 + l * F * 3 * F, uw2T_base + l * LAYER_T, F, 3 * F);
    }
    add(ro_w1, roT, F, 64);
    P.n = pi;

    init_kernel<<<N_ATOMS, F, 0, stream>>>(Z, emb, s);
    hipMemsetAsync(v, 0, (size_t)N_ATOMS * 3 * F * sizeof(float), stream);
    hipMemsetAsync(v_h, 0, (size_t)N_ATOMS * 3 * F * sizeof(__half), stream);
    hipMemsetAsync(count, 0, (size_t)N_ATOMS * sizeof(int), stream);
    fill_buckets<<<(N_EDGES + 255) / 256, 256, 0, stream>>>(eidx, count, bucket);
    transpose_all<<<nb, 256, 0, stream>>>(P);

    for (int l = 0; l < NL; ++l) {
        phi_kernel<<<N_ATOMS / 8, 128, 0, stream>>>(
            s, w1T_base + l * LAYER_T, msg_b1 + l * F,
            w2T_base + l * LAYER_T, msg_b2 + l * 3 * F, phi_h);
        edge_agg_kernel<<<N_ATOMS, 128, 0, stream>>>(
            count, bucket, eidx, ediff, edist,
            filt_w + l * B * 3 * F, filt_b + l * 3 * F, phi_h, v_h, ds, dv);
        update_kernel<<<N_ATOMS / 8, 128, 0, stream>>>(
            s, v, v_h, ds, dv, UT_base + l * LAYER_T, VT_base + l * LAYER_T,
            uw1T_base + l * LAYER_T, upd_b1 + l * F,
            uw2T_base + l * LAYER_T, upd_b2 + l * 3 * F);
    }
    readout_kernel<<<(N_ATOMS + 15) / 16, 64, 0, stream>>>(s, roT, ro_b1, ro_w2, ro_b2, out);
}